// Round 16
// baseline (557.527 us; speedup 1.0000x reference)
//
#include <hip/hip_runtime.h>

#define TT    1024
#define DIN   8
#define RSLOT 64          // h1 ring slots (8 KB LDS)

typedef float f32x2 __attribute__((ext_vector_type(2)));

// sigma(x) = 1 / (1 + exp2(-x*log2e))
__device__ __forceinline__ float fsig(float x) {
    float e = __builtin_amdgcn_exp2f(-1.4426950408889634f * x);
    return __builtin_amdgcn_rcpf(1.0f + e);
}
// tanh(x) = 2*sigma(2x) - 1
__device__ __forceinline__ float ftanh_(float x) {
    float e = __builtin_amdgcn_exp2f(-2.8853900817779268f * x);
    return 2.0f * __builtin_amdgcn_rcpf(1.0f + e) - 1.0f;
}
// DPP pair swap (lane 2k <-> 2k+1)
template<int CTRL>
__device__ __forceinline__ float dppf(float v) {
    return __uint_as_float((unsigned)__builtin_amdgcn_update_dpp(
        0, (int)__float_as_uint(v), CTRL, 0xF, 0xF, true));
}
// packed 2-wide FMA -> v_pk_fma_f32
__device__ __forceinline__ f32x2 pkfma(f32x2 a, f32x2 b, f32x2 c) {
    return __builtin_elementwise_fma(a, b, c);
}

// ============================ kernel 1: recurrence ============================
// 2 decoupled waves per batch element (block=128, grid=256); no s_barrier in
// the main loops. Wave0 = whole layer 1 (R2-verified pair layout, 80 wt
// floats = 40 f32x2). Wave1 = whole layer 2 (128 wt floats = 64 f32x2).
// h1 flows wave0 -> wave1 via a 64-slot LDS ring + monotonic progress flags.
//
// R15 failed on (a) wave1 register residency (demand ~90, granted 88 ->
// per-step cache refetch) and (b) per-step serialized flag polls with s_sleep
// quantization. This round: (a) trimmed working set; (b) SPECULATIVE consume:
// wave1 issues flag read + ring reads + dot concurrently; flag >= t+2 proves
// ring[t] was written+drained one full wave0-step (~450cy) before the flag
// value existed, so concurrently-issued data reads (<=~150cy earlier) cannot
// predate it -> zero sync cost on the common path. Insufficient margin ->
// spin (no sleep) + authoritative redo. Wave0 bumps its flag every 2 steps,
// wave1 every 16 (backpressure only).
__global__ void __launch_bounds__(128, 1)
lstm_rec(const float* __restrict__ x,
         const float* __restrict__ Wih1, const float* __restrict__ Whh1,
         const float* __restrict__ bih1, const float* __restrict__ bhh1,
         const float* __restrict__ Wih2, const float* __restrict__ Whh2,
         const float* __restrict__ bih2, const float* __restrict__ bhh2,
         float* __restrict__ out)
{
    const int tid = threadIdx.x;
    const int wv  = tid >> 6;          // 0 = layer1, 1 = layer2
    const int l   = tid & 63;
    const int q   = l & 1;
    const int j   = l >> 1;            // hidden unit 0..31
    const int b   = blockIdx.x;
    const int r0  = q ? (32 + j) : j;          // i | f
    const int r1  = q ? (96 + j) : (64 + j);   // g | o

    __shared__ float ring[RSLOT][32];  // h1 history ring (slot t & 63)
    __shared__ float hs2[32];          // wave1's own h2 (single buffer:
                                       // per-wave DS ops complete in order)
    __shared__ int   prog[2];          // [0] wave0 steps done, [1] wave1
    for (int i = tid; i < RSLOT*32; i += 128) ((float*)ring)[i] = 0.f;
    if (tid < 32) hs2[tid] = 0.f;
    if (tid < 2)  prog[tid] = 0;
    __syncthreads();                   // init visible (only barrier)

    volatile int* vp0 = (volatile int*)&prog[0];
    volatile int* vp1 = (volatile int*)&prog[1];

    if (wv == 0) {
        // ================= wave0: layer 1 (self-contained recurrence) ========
        f32x2 wh0[16], wh1[16], wx0[4], wx1[4];
#pragma unroll
        for (int k = 0; k < 16; ++k) {
            wh0[k] = reinterpret_cast<const f32x2*>(Whh1 + r0*32)[k];
            wh1[k] = reinterpret_cast<const f32x2*>(Whh1 + r1*32)[k];
        }
#pragma unroll
        for (int k = 0; k < 4; ++k) {
            wx0[k] = reinterpret_cast<const f32x2*>(Wih1 + r0*DIN)[k];
            wx1[k] = reinterpret_cast<const f32x2*>(Wih1 + r1*DIN)[k];
        }
        const float b0 = bih1[r0] + bhh1[r0];
        const float b1 = bih1[r1] + bhh1[r1];
        float c1 = 0.f;
        const float* __restrict__ xb = x + (size_t)b * (TT*DIN);
        float4 xa = reinterpret_cast<const float4*>(xb)[0];
        float4 xc = reinterpret_cast<const float4*>(xb)[1];
        int xoff = DIN;
        int w1seen = 0;

#pragma unroll 1
        for (int t = 0; t < TT; ++t) {
            // backpressure: about to overwrite ring[t&63] = slot of h1(t-64);
            // wave1 must have consumed it (flag granularity 16, margin 4)
            if (t - w1seen >= RSLOT - 20) {
                do { w1seen = *vp1; } while (t - w1seen >= RSLOT - 20);
            }
            asm volatile("" ::: "memory");

            f32x2 a0 = {b0, 0.f}, a1 = {0.f, 0.f};
            f32x2 g0 = {b1, 0.f}, g1 = {0.f, 0.f};
            const float* hp = &ring[(t + RSLOT - 1) & (RSLOT-1)][0];
#pragma unroll
            for (int qq = 0; qq < 8; ++qq) {        // h1(t-1), uniform b128
                float4 v = reinterpret_cast<const float4*>(hp)[qq];
                f32x2 lo = {v.x, v.y}, hi = {v.z, v.w};
                a0 = pkfma(wh0[2*qq],   lo, a0);
                a1 = pkfma(wh0[2*qq+1], hi, a1);
                g0 = pkfma(wh1[2*qq],   lo, g0);
                g1 = pkfma(wh1[2*qq+1], hi, g1);
            }
            f32x2 xp0 = {xa.x, xa.y}, xp1 = {xa.z, xa.w};
            f32x2 xp2 = {xc.x, xc.y}, xp3 = {xc.z, xc.w};
            a0 = pkfma(wx0[0], xp0, a0);  a1 = pkfma(wx0[1], xp1, a1);
            a0 = pkfma(wx0[2], xp2, a0);  a1 = pkfma(wx0[3], xp3, a1);
            g0 = pkfma(wx1[0], xp0, g0);  g1 = pkfma(wx1[1], xp1, g1);
            g0 = pkfma(wx1[2], xp2, g0);  g1 = pkfma(wx1[3], xp3, g1);
            xa = reinterpret_cast<const float4*>(xb + xoff)[0];   // prefetch
            xc = reinterpret_cast<const float4*>(xb + xoff)[1];
            xoff = (xoff + DIN > (TT-1)*DIN) ? (TT-1)*DIN : (xoff + DIN);

            float p0 = (a0.x + a0.y) + (a1.x + a1.y);
            float p1 = (g0.x + g0.y) + (g1.x + g1.y);
            float A  = fsig(p0);                    // sig(i) even | sig(f) odd
            float uu = q ? p1 : (p1 + p1);
            float S  = fsig(uu);
            float Bv = q ? S : (S + S - 1.0f);      // tanh(g) even | sig(o) odd
            float An = dppf<0xB1>(A), Bn = dppf<0xB1>(Bv);
            float si = q ? An : A,  sf = q ? A  : An;
            float tg = q ? Bn : Bv, so = q ? Bv : Bn;
            c1 = sf * c1 + si * tg;
            float h1v = so * ftanh_(c1);
            if (!q) ring[t & (RSLOT-1)][j] = h1v;   // publish h1(t)
            if (t & 1) {                            // flag every 2 steps
                asm volatile("s_waitcnt lgkmcnt(0)" ::: "memory");
                if (l == 0) *vp0 = t + 1;
            }
        }
        asm volatile("s_waitcnt lgkmcnt(0)" ::: "memory");
        if (l == 0) *vp0 = TT + 2;                  // final flag (covers odd tail)
    } else {
        // ================= wave1: layer 2 =================
        f32x2 u0w[16], u1w[16], v0w[16], v1w[16];
#pragma unroll
        for (int k = 0; k < 16; ++k) {
            u0w[k] = reinterpret_cast<const f32x2*>(Whh2 + r0*32)[k];  // x h2
            u1w[k] = reinterpret_cast<const f32x2*>(Whh2 + r1*32)[k];
            v0w[k] = reinterpret_cast<const f32x2*>(Wih2 + r0*32)[k];  // x h1
            v1w[k] = reinterpret_cast<const f32x2*>(Wih2 + r1*32)[k];
        }
        const float b0 = bih2[r0] + bhh2[r0];
        const float b1 = bih2[r1] + bhh2[r1];
        float c2 = 0.f;
        float* __restrict__ outb = out + (size_t)b * (TT*80);
        int o2 = 0;

#pragma unroll 1
        for (int t = 0; t < TT; ++t) {
            float p0, p1;
            // full dot over [h1(t) from ring | h2(t-1) from hs2]
            auto dot = [&](void) {
                f32x2 a0 = {b0, 0.f}, a1 = {0.f, 0.f};
                f32x2 g0 = {b1, 0.f}, g1 = {0.f, 0.f};
                const float* rp = &ring[t & (RSLOT-1)][0];
#pragma unroll
                for (int qq = 0; qq < 8; ++qq) {
                    float4 v = reinterpret_cast<const float4*>(rp)[qq];
                    f32x2 lo = {v.x, v.y}, hi = {v.z, v.w};
                    a0 = pkfma(v0w[2*qq],   lo, a0);
                    a1 = pkfma(v0w[2*qq+1], hi, a1);
                    g0 = pkfma(v1w[2*qq],   lo, g0);
                    g1 = pkfma(v1w[2*qq+1], hi, g1);
                }
#pragma unroll
                for (int qq = 0; qq < 8; ++qq) {    // own h2: always safe
                    float4 v = reinterpret_cast<const float4*>(&hs2[0])[qq];
                    f32x2 lo = {v.x, v.y}, hi = {v.z, v.w};
                    a0 = pkfma(u0w[2*qq],   lo, a0);
                    a1 = pkfma(u0w[2*qq+1], hi, a1);
                    g0 = pkfma(u1w[2*qq],   lo, g0);
                    g1 = pkfma(u1w[2*qq+1], hi, g1);
                }
                p0 = (a0.x + a0.y) + (a1.x + a1.y);
                p1 = (g0.x + g0.y) + (g1.x + g1.y);
            };

            // speculative: flag read concurrent with data reads + dot
            int f = *vp0;
            dot();
            if (f < t + 2) {                        // margin too small
                while (*vp0 < t + 1) { /* spin, no sleep */ }
                asm volatile("" ::: "memory");
                dot();                              // authoritative redo
            }

            float A  = fsig(p0);
            float uu = q ? p1 : (p1 + p1);
            float S  = fsig(uu);
            float Bv = q ? S : (S + S - 1.0f);
            float An = dppf<0xB1>(A), Bn = dppf<0xB1>(Bv);
            float si = q ? An : A,  sf = q ? A  : An;
            float tg = q ? Bn : Bv, so = q ? Bv : Bn;
            c2 = sf * c2 + si * tg;
            float h2v = so * ftanh_(c2);
            if (!q) { hs2[j] = h2v; outb[o2 + j] = h2v; }   // publish + scratch
            o2 += 80;
            if ((t & 15) == 15) {                   // consumption flag
                asm volatile("s_waitcnt lgkmcnt(0)" ::: "memory");
                if (l == 0) *vp1 = t + 1;
            }
        }
    }
}

// ============================ kernel 2: out linear ============================
// out[row][0:80] = h2[row] @ Wlin^T + blin, h2 scratch = out[row][0:32].
// Unchanged from round 11 (verified; ~17 us).
__global__ void __launch_bounds__(256, 4)
out_lin(const float* __restrict__ Wlin, const float* __restrict__ blin,
        float* __restrict__ out, int ntiles)
{
    __shared__ float wl[80][36];
    __shared__ float bl[80];
    __shared__ float ht[16][36];
    const int tid = threadIdx.x;

#pragma unroll 1
    for (int i = tid; i < 640; i += 256) {          // 80 rows x 8 float4
        const int cc = i >> 3, qq = i & 7;
        float4 v = reinterpret_cast<const float4*>(Wlin)[i];
        *reinterpret_cast<float4*>(&wl[cc][qq*4]) = v;
    }
    if (tid < 80) bl[tid] = blin[tid];
    __syncthreads();

    const int row = tid >> 4;   // 0..15
    const int cl  = tid & 15;   // 0..15

#pragma unroll 1
    for (int tile = blockIdx.x; tile < ntiles; tile += gridDim.x) {
        const size_t base = (size_t)tile * 16;
        if (tid < 128) {                            // stage 16 rows of h2
            const int r = tid >> 3, qq = tid & 7;
            float4 v = *reinterpret_cast<const float4*>(out + (base + r)*80 + qq*4);
            *reinterpret_cast<float4*>(&ht[r][qq*4]) = v;
        }
        __syncthreads();

        float hr[32];
#pragma unroll
        for (int jj = 0; jj < 8; ++jj) {
            float4 v = *reinterpret_cast<const float4*>(&ht[row][jj*4]);
            hr[4*jj]=v.x; hr[4*jj+1]=v.y; hr[4*jj+2]=v.z; hr[4*jj+3]=v.w;
        }
        float res[5];
#pragma unroll
        for (int cj = 0; cj < 5; ++cj) {
            const int cc = cl + 16*cj;
            float a0 = bl[cc], a1 = 0.f, a2 = 0.f, a3 = 0.f;
#pragma unroll
            for (int k = 0; k < 32; k += 4) {
                a0 += wl[cc][k]  *hr[k];   a1 += wl[cc][k+1]*hr[k+1];
                a2 += wl[cc][k+2]*hr[k+2]; a3 += wl[cc][k+3]*hr[k+3];
            }
            res[cj] = (a0 + a1) + (a2 + a3);
        }
        __syncthreads();   // ht reads complete before next tile's staging
#pragma unroll
        for (int cj = 0; cj < 5; ++cj)
            out[(base + row)*80 + cl + 16*cj] = res[cj];
    }
}

extern "C" void kernel_launch(void* const* d_in, const int* in_sizes, int n_in,
                              void* d_out, int out_size, void* d_ws, size_t ws_size,
                              hipStream_t stream) {
    const float* x    = (const float*)d_in[0];
    const float* Wih1 = (const float*)d_in[1];
    const float* Whh1 = (const float*)d_in[2];
    const float* bih1 = (const float*)d_in[3];
    const float* bhh1 = (const float*)d_in[4];
    const float* Wih2 = (const float*)d_in[5];
    const float* Whh2 = (const float*)d_in[6];
    const float* bih2 = (const float*)d_in[7];
    const float* bhh2 = (const float*)d_in[8];
    const float* Wlin = (const float*)d_in[9];
    const float* blin = (const float*)d_in[10];

    const int B = in_sizes[0] / (TT * DIN);   // 256
    const int ntiles = (B * TT) / 16;         // 16384

    hipLaunchKernelGGL(lstm_rec, dim3(B), dim3(128), 0, stream,
                       x, Wih1, Whh1, bih1, bhh1,
                       Wih2, Whh2, bih2, bhh2,
                       (float*)d_out);
    hipLaunchKernelGGL(out_lin, dim3(2048), dim3(256), 0, stream,
                       Wlin, blin, (float*)d_out, ntiles);
}

// Round 17
// 506.143 us; speedup vs baseline: 1.1015x; 1.1015x over previous
//
#include <hip/hip_runtime.h>

#define TT    1024
#define DIN   8
#define RSLOT 64          // h1 ring slots (8 KB LDS)

typedef float f32x2 __attribute__((ext_vector_type(2)));

// sigma(x) = 1 / (1 + exp2(-x*log2e))
__device__ __forceinline__ float fsig(float x) {
    float e = __builtin_amdgcn_exp2f(-1.4426950408889634f * x);
    return __builtin_amdgcn_rcpf(1.0f + e);
}
// tanh(x) = 2*sigma(2x) - 1
__device__ __forceinline__ float ftanh_(float x) {
    float e = __builtin_amdgcn_exp2f(-2.8853900817779268f * x);
    return 2.0f * __builtin_amdgcn_rcpf(1.0f + e) - 1.0f;
}
// DPP pair swap (lane 2k <-> 2k+1)
template<int CTRL>
__device__ __forceinline__ float dppf(float v) {
    return __uint_as_float((unsigned)__builtin_amdgcn_update_dpp(
        0, (int)__float_as_uint(v), CTRL, 0xF, 0xF, true));
}
// packed 2-wide FMA -> v_pk_fma_f32
__device__ __forceinline__ f32x2 pkfma(f32x2 a, f32x2 b, f32x2 c) {
    return __builtin_elementwise_fma(a, b, c);
}

// ============================ kernel 1: recurrence ============================
// 2 decoupled waves per batch element (block=128); no s_barrier in the main
// loops. Wave0 = layer 1 (80 wt floats/lane), wave1 = layer 2 (128/lane).
// h1 flows wave0 -> wave1 via 64-slot LDS ring + monotonic progress flags
// (producer drains lgkmcnt(0) before bumping; protocol validated R15/R16).
//
// R16 post-mortem: cadences are near-equal, so the consumer's speculative
// margin never builds -> spec check failed EVERY step -> spin + full dot redo
// (~+350cy) + serialized poll (~130cy) per step. Fix: BATCHED CACHED-FLAG
// consumption. One poll of the producer flag covers all steps t < fcache;
// wave0 is structurally faster (no 2nd 8-read block), builds a 30-50 step
// lead (ring-bounded), so polls amortize to ~10cy/step and the dot is read
// exactly once, unconditionally safe. Producer backpressure spins with
// s_sleep (its idle time is free; keeps spin off the shared LDS pipe).
__global__ void __launch_bounds__(128, 1)
lstm_rec(const float* __restrict__ x,
         const float* __restrict__ Wih1, const float* __restrict__ Whh1,
         const float* __restrict__ bih1, const float* __restrict__ bhh1,
         const float* __restrict__ Wih2, const float* __restrict__ Whh2,
         const float* __restrict__ bih2, const float* __restrict__ bhh2,
         float* __restrict__ out)
{
    const int tid = threadIdx.x;
    const int wv  = tid >> 6;          // 0 = layer1, 1 = layer2
    const int l   = tid & 63;
    const int q   = l & 1;
    const int j   = l >> 1;            // hidden unit 0..31
    const int b   = blockIdx.x;
    const int r0  = q ? (32 + j) : j;          // i | f
    const int r1  = q ? (96 + j) : (64 + j);   // g | o

    __shared__ float ring[RSLOT][32];  // h1 history ring (slot t & 63)
    __shared__ float hs2[32];          // wave1's own h2 (same-wave DS ordering)
    __shared__ int   prog[2];          // [0] wave0 steps done, [1] wave1
    for (int i = tid; i < RSLOT*32; i += 128) ((float*)ring)[i] = 0.f;
    if (tid < 32) hs2[tid] = 0.f;
    if (tid < 2)  prog[tid] = 0;
    __syncthreads();                   // init visible (only barrier)

    volatile int* vp0 = (volatile int*)&prog[0];
    volatile int* vp1 = (volatile int*)&prog[1];

    if (wv == 0) {
        // ================= wave0: layer 1 (self-contained recurrence) ========
        f32x2 wh0[16], wh1[16], wx0[4], wx1[4];
#pragma unroll
        for (int k = 0; k < 16; ++k) {
            wh0[k] = reinterpret_cast<const f32x2*>(Whh1 + r0*32)[k];
            wh1[k] = reinterpret_cast<const f32x2*>(Whh1 + r1*32)[k];
        }
#pragma unroll
        for (int k = 0; k < 4; ++k) {
            wx0[k] = reinterpret_cast<const f32x2*>(Wih1 + r0*DIN)[k];
            wx1[k] = reinterpret_cast<const f32x2*>(Wih1 + r1*DIN)[k];
        }
        const float b0 = bih1[r0] + bhh1[r0];
        const float b1 = bih1[r1] + bhh1[r1];
        float c1 = 0.f;
        const float* __restrict__ xb = x + (size_t)b * (TT*DIN);
        float4 xa = reinterpret_cast<const float4*>(xb)[0];
        float4 xc = reinterpret_cast<const float4*>(xb)[1];
        int xoff = DIN;
        int w1seen = 0;

#pragma unroll 1
        for (int t = 0; t < TT; ++t) {
            // backpressure: don't run more than RSLOT-12 ahead of wave1
            // (wave1 flags every 16 -> true lag <= (t - w1seen) + 16 < 64) ✓
            if (t - w1seen >= RSLOT - 12) {
                do { __builtin_amdgcn_s_sleep(8); w1seen = *vp1; }
                while (t - w1seen >= RSLOT - 12);
            }
            asm volatile("" ::: "memory");

            f32x2 a0 = {b0, 0.f}, a1 = {0.f, 0.f};
            f32x2 g0 = {b1, 0.f}, g1 = {0.f, 0.f};
            const float* hp = &ring[(t + RSLOT - 1) & (RSLOT-1)][0];
#pragma unroll
            for (int qq = 0; qq < 8; ++qq) {        // h1(t-1), uniform b128
                float4 v = reinterpret_cast<const float4*>(hp)[qq];
                f32x2 lo = {v.x, v.y}, hi = {v.z, v.w};
                a0 = pkfma(wh0[2*qq],   lo, a0);
                a1 = pkfma(wh0[2*qq+1], hi, a1);
                g0 = pkfma(wh1[2*qq],   lo, g0);
                g1 = pkfma(wh1[2*qq+1], hi, g1);
            }
            f32x2 xp0 = {xa.x, xa.y}, xp1 = {xa.z, xa.w};
            f32x2 xp2 = {xc.x, xc.y}, xp3 = {xc.z, xc.w};
            a0 = pkfma(wx0[0], xp0, a0);  a1 = pkfma(wx0[1], xp1, a1);
            a0 = pkfma(wx0[2], xp2, a0);  a1 = pkfma(wx0[3], xp3, a1);
            g0 = pkfma(wx1[0], xp0, g0);  g1 = pkfma(wx1[1], xp1, g1);
            g0 = pkfma(wx1[2], xp2, g0);  g1 = pkfma(wx1[3], xp3, g1);
            xa = reinterpret_cast<const float4*>(xb + xoff)[0];   // prefetch
            xc = reinterpret_cast<const float4*>(xb + xoff)[1];
            xoff = (xoff + DIN > (TT-1)*DIN) ? (TT-1)*DIN : (xoff + DIN);

            float p0 = (a0.x + a0.y) + (a1.x + a1.y);
            float p1 = (g0.x + g0.y) + (g1.x + g1.y);
            float A  = fsig(p0);                    // sig(i) even | sig(f) odd
            float uu = q ? p1 : (p1 + p1);
            float S  = fsig(uu);
            float Bv = q ? S : (S + S - 1.0f);      // tanh(g) even | sig(o) odd
            float An = dppf<0xB1>(A), Bn = dppf<0xB1>(Bv);
            float si = q ? An : A,  sf = q ? A  : An;
            float tg = q ? Bn : Bv, so = q ? Bv : Bn;
            c1 = sf * c1 + si * tg;
            float h1v = so * ftanh_(c1);
            if (!q) ring[t & (RSLOT-1)][j] = h1v;   // publish h1(t)
            if (t & 1) {                            // flag every 2 steps
                asm volatile("s_waitcnt lgkmcnt(0)" ::: "memory");
                if (l == 0) *vp0 = t + 1;
            }
        }
        asm volatile("s_waitcnt lgkmcnt(0)" ::: "memory");
        if (l == 0) *vp0 = TT + 2;                  // final flag (covers tail)
    } else {
        // ================= wave1: layer 2 (batched cached-flag consume) ======
        f32x2 u0w[16], u1w[16], v0w[16], v1w[16];
#pragma unroll
        for (int k = 0; k < 16; ++k) {
            u0w[k] = reinterpret_cast<const f32x2*>(Whh2 + r0*32)[k];  // x h2
            u1w[k] = reinterpret_cast<const f32x2*>(Whh2 + r1*32)[k];
            v0w[k] = reinterpret_cast<const f32x2*>(Wih2 + r0*32)[k];  // x h1
            v1w[k] = reinterpret_cast<const f32x2*>(Wih2 + r1*32)[k];
        }
        const float b0 = bih2[r0] + bhh2[r0];
        const float b1 = bih2[r1] + bhh2[r1];
        float c2 = 0.f;
        float* __restrict__ outb = out + (size_t)b * (TT*80);
        int o2 = 0;
        int fcache = 0;    // producer steps known complete; one poll covers
                           // all steps t < fcache (wave0 runs ahead -> rare)

#pragma unroll 1
        for (int t = 0; t < TT; ++t) {
            if (t >= fcache) {                      // need h1(t): f >= t+1
                do { fcache = *vp0; } while (t >= fcache);
                asm volatile("" ::: "memory");      // no data-read hoisting
            }

            f32x2 a0 = {b0, 0.f}, a1 = {0.f, 0.f};
            f32x2 g0 = {b1, 0.f}, g1 = {0.f, 0.f};
            const float* rp = &ring[t & (RSLOT-1)][0];
#pragma unroll
            for (int qq = 0; qq < 8; ++qq) {        // h1(t) from ring
                float4 v = reinterpret_cast<const float4*>(rp)[qq];
                f32x2 lo = {v.x, v.y}, hi = {v.z, v.w};
                a0 = pkfma(v0w[2*qq],   lo, a0);
                a1 = pkfma(v0w[2*qq+1], hi, a1);
                g0 = pkfma(v1w[2*qq],   lo, g0);
                g1 = pkfma(v1w[2*qq+1], hi, g1);
            }
#pragma unroll
            for (int qq = 0; qq < 8; ++qq) {        // h2(t-1) own buffer
                float4 v = reinterpret_cast<const float4*>(&hs2[0])[qq];
                f32x2 lo = {v.x, v.y}, hi = {v.z, v.w};
                a0 = pkfma(u0w[2*qq],   lo, a0);
                a1 = pkfma(u0w[2*qq+1], hi, a1);
                g0 = pkfma(u1w[2*qq],   lo, g0);
                g1 = pkfma(u1w[2*qq+1], hi, g1);
            }
            float p0 = (a0.x + a0.y) + (a1.x + a1.y);
            float p1 = (g0.x + g0.y) + (g1.x + g1.y);

            float A  = fsig(p0);
            float uu = q ? p1 : (p1 + p1);
            float S  = fsig(uu);
            float Bv = q ? S : (S + S - 1.0f);
            float An = dppf<0xB1>(A), Bn = dppf<0xB1>(Bv);
            float si = q ? An : A,  sf = q ? A  : An;
            float tg = q ? Bn : Bv, so = q ? Bv : Bn;
            c2 = sf * c2 + si * tg;
            float h2v = so * ftanh_(c2);
            if (!q) { hs2[j] = h2v; outb[o2 + j] = h2v; }   // publish + scratch
            o2 += 80;
            if ((t & 15) == 15) {                   // consumption flag
                asm volatile("s_waitcnt lgkmcnt(0)" ::: "memory");
                if (l == 0) *vp1 = t + 1;
            }
        }
    }
}

// ============================ kernel 2: out linear ============================
// out[row][0:80] = h2[row] @ Wlin^T + blin, h2 scratch = out[row][0:32].
// Unchanged from round 11 (verified; ~17 us).
__global__ void __launch_bounds__(256, 4)
out_lin(const float* __restrict__ Wlin, const float* __restrict__ blin,
        float* __restrict__ out, int ntiles)
{
    __shared__ float wl[80][36];
    __shared__ float bl[80];
    __shared__ float ht[16][36];
    const int tid = threadIdx.x;

#pragma unroll 1
    for (int i = tid; i < 640; i += 256) {          // 80 rows x 8 float4
        const int cc = i >> 3, qq = i & 7;
        float4 v = reinterpret_cast<const float4*>(Wlin)[i];
        *reinterpret_cast<float4*>(&wl[cc][qq*4]) = v;
    }
    if (tid < 80) bl[tid] = blin[tid];
    __syncthreads();

    const int row = tid >> 4;   // 0..15
    const int cl  = tid & 15;   // 0..15

#pragma unroll 1
    for (int tile = blockIdx.x; tile < ntiles; tile += gridDim.x) {
        const size_t base = (size_t)tile * 16;
        if (tid < 128) {                            // stage 16 rows of h2
            const int r = tid >> 3, qq = tid & 7;
            float4 v = *reinterpret_cast<const float4*>(out + (base + r)*80 + qq*4);
            *reinterpret_cast<float4*>(&ht[r][qq*4]) = v;
        }
        __syncthreads();

        float hr[32];
#pragma unroll
        for (int jj = 0; jj < 8; ++jj) {
            float4 v = *reinterpret_cast<const float4*>(&ht[row][jj*4]);
            hr[4*jj]=v.x; hr[4*jj+1]=v.y; hr[4*jj+2]=v.z; hr[4*jj+3]=v.w;
        }
        float res[5];
#pragma unroll
        for (int cj = 0; cj < 5; ++cj) {
            const int cc = cl + 16*cj;
            float a0 = bl[cc], a1 = 0.f, a2 = 0.f, a3 = 0.f;
#pragma unroll
            for (int k = 0; k < 32; k += 4) {
                a0 += wl[cc][k]  *hr[k];   a1 += wl[cc][k+1]*hr[k+1];
                a2 += wl[cc][k+2]*hr[k+2]; a3 += wl[cc][k+3]*hr[k+3];
            }
            res[cj] = (a0 + a1) + (a2 + a3);
        }
        __syncthreads();   // ht reads complete before next tile's staging
#pragma unroll
        for (int cj = 0; cj < 5; ++cj)
            out[(base + row)*80 + cl + 16*cj] = res[cj];
    }
}

extern "C" void kernel_launch(void* const* d_in, const int* in_sizes, int n_in,
                              void* d_out, int out_size, void* d_ws, size_t ws_size,
                              hipStream_t stream) {
    const float* x    = (const float*)d_in[0];
    const float* Wih1 = (const float*)d_in[1];
    const float* Whh1 = (const float*)d_in[2];
    const float* bih1 = (const float*)d_in[3];
    const float* bhh1 = (const float*)d_in[4];
    const float* Wih2 = (const float*)d_in[5];
    const float* Whh2 = (const float*)d_in[6];
    const float* bih2 = (const float*)d_in[7];
    const float* bhh2 = (const float*)d_in[8];
    const float* Wlin = (const float*)d_in[9];
    const float* blin = (const float*)d_in[10];

    const int B = in_sizes[0] / (TT * DIN);   // 256
    const int ntiles = (B * TT) / 16;         // 16384

    hipLaunchKernelGGL(lstm_rec, dim3(B), dim3(128), 0, stream,
                       x, Wih1, Whh1, bih1, bhh1,
                       Wih2, Whh2, bih2, bhh2,
                       (float*)d_out);
    hipLaunchKernelGGL(out_lin, dim3(2048), dim3(256), 0, stream,
                       Wlin, blin, (float*)d_out, ntiles);
}

// Round 18
// 380.292 us; speedup vs baseline: 1.4660x; 1.3309x over previous
//
#include <hip/hip_runtime.h>

#define TT  1024
#define DIN 8

typedef float f32x2 __attribute__((ext_vector_type(2)));

// sigma(x) = 1 / (1 + exp2(-x*log2e))
__device__ __forceinline__ float fsig(float x) {
    float e = __builtin_amdgcn_exp2f(-1.4426950408889634f * x);
    return __builtin_amdgcn_rcpf(1.0f + e);
}
// tanh(x) = 2*sigma(2x) - 1
__device__ __forceinline__ float ftanh_(float x) {
    float e = __builtin_amdgcn_exp2f(-2.8853900817779268f * x);
    return 2.0f * __builtin_amdgcn_rcpf(1.0f + e) - 1.0f;
}
// DPP lane permute, compile-time ctrl.
// 0xB1 = quad_perm(1,0,3,2): XOR-1. 0x4E = quad_perm(2,3,0,1): XOR-2.
// 0x114 = row_shr:4, 0x112 = row_shr:2, 0x102 = row_shl:2.
template<int CTRL>
__device__ __forceinline__ float dppf(float v) {
    return __uint_as_float((unsigned)__builtin_amdgcn_update_dpp(
        0, (int)__float_as_uint(v), CTRL, 0xF, 0xF, true));
}
// packed 2-wide FMA: lowers to v_pk_fma_f32 (full-rate on CDNA3/4)
__device__ __forceinline__ f32x2 pkfma(f32x2 a, f32x2 b, f32x2 c) {
    return __builtin_elementwise_fma(a, b, c);
}
// lgkm-only barrier: ds_writes visible + ds_reads of the old parity slot
// complete. Global stores (h2 scratch, never read here) and the x prefetch
// stay in flight across it.
__device__ __forceinline__ void bar_lgkm() {
    asm volatile("s_waitcnt lgkmcnt(0)\n\ts_barrier" ::: "memory");
}

// ============================ kernel 1: recurrence ============================
// ROUND-14 OPTIMUM RESTORED (measured 380.5 us total; best of 17 rounds).
// Interval model (evidence R7-R17): ~880 cy/step = DS-queue burst (~350-400,
// 8 waves x ~40 b128 ops through the single per-CU LDS pipe) + irreducible
// serial chain (~450: ds_read lat -> dot -> DPP reduce -> exp/rcp -> cell ->
// tanh -> write drain -> barrier) + barrier wake. VALU issue (427 cy/SIMD,
// pk-FMA-halved) hides inside the latency shadow. Async decoupling (R15-17),
// more TLP (R13), fewer DS ops at VALU cost (R12) all regressed.
//
// 8 waves / batch element. Waves 0-3: layer 1 (2 lanes/gate row, part = half
// of the 32-dot; 4 b128 LDS reads + 10 pk-FMA). Waves 4-7: layer 2 quad-split
// (quad = {g,g^1}x{part}; 4 b128 reads = 16 floats; 2 rows x 8 pk-FMA;
// 3-DPP reduction assembles both rows' full 64-dots). Cell update via DPP
// row_shr4/shr2/shl2. h2(t) fire-and-forget to out[b][t][0:32] scratch for
// kernel 2. One lgkm barrier per timestep-iteration.
__global__ void __launch_bounds__(512, 2)
lstm_rec(const float* __restrict__ x,
         const float* __restrict__ Wih1, const float* __restrict__ Whh1,
         const float* __restrict__ bih1, const float* __restrict__ bhh1,
         const float* __restrict__ Wih2, const float* __restrict__ Whh2,
         const float* __restrict__ bih2, const float* __restrict__ bhh2,
         float* __restrict__ out)
{
    const int tid  = threadIdx.x;
    const int wv   = tid >> 6;         // wave 0..7
    const int l    = tid & 63;
    const int part = l & 1;
    const int g    = (l >> 1) & 3;     // 0=i 1=f 2=g 3=o
    const int ul   = l >> 3;           // unit-local 0..7
    const int b    = blockIdx.x;
    const bool isL1 = (wv < 4);
    const int  wu   = isL1 ? wv : (wv - 4);
    const int  unit = wu*8 + ul;       // hidden unit 0..31
    const bool isg  = (g == 2);

    __shared__ float hb1[2][32];       // h1 by parity
    __shared__ float hb2[2][32];       // h2 by parity
    if (tid < 64)       ((float*)hb1)[tid]      = 0.f;
    else if (tid < 128) ((float*)hb2)[tid - 64] = 0.f;

    // ---- per-lane weights (packed pairs) ----
    f32x2 wgh[8];                // L1: Whh1 half row (16 floats)
    f32x2 wgx[2];                // L1: Wih1 quarter (4 floats)
    f32x2 wa2[8], wb2[8];        // L2: 16 wts of even row, 16 of odd row
    float bias = 0.f;

    if (isL1) {
        const int R = g*32 + unit;
        const float* wsrc = Whh1 + R*32 + part*16;
#pragma unroll
        for (int qq = 0; qq < 8; ++qq)
            wgh[qq] = reinterpret_cast<const f32x2*>(wsrc)[qq];
        const float* xsrc = Wih1 + R*DIN + part*4;
        wgx[0] = reinterpret_cast<const f32x2*>(xsrc)[0];
        wgx[1] = reinterpret_cast<const f32x2*>(xsrc)[1];
        if (!part) bias = bih1[R] + bhh1[R];
    } else {
        const int hs = g & 1;            // which 16-half of the input vector
        const int k2 = g >> 1;           // row-pair selector
        const int Re = (2*k2)*32 + unit;     // even row of pair
        const int Ro = (2*k2+1)*32 + unit;   // odd row of pair
        const int Rw = g*32 + unit;          // own row (bias)
        const float* base = part ? Wih2 : Whh2;  // part1: h1-input, part0: h2
#pragma unroll
        for (int qq = 0; qq < 8; ++qq) {
            wa2[qq] = reinterpret_cast<const f32x2*>(base + Re*32 + hs*16)[qq];
            wb2[qq] = reinterpret_cast<const f32x2*>(base + Ro*32 + hs*16)[qq];
        }
        bias = bih2[Rw] + bhh2[Rw];      // added once, post-reduction (own row)
    }

    float c = 0.f;   // valid on lanes l&7 in {4,5}; bounded garbage elsewhere

    const float* __restrict__ xb = x   + (size_t)b * (TT*DIN);
    float* __restrict__ outb     = out + (size_t)b * (TT*80);

    f32x2 xc0 = {0.f, 0.f}, xc1 = {0.f, 0.f};
    if (isL1) {
        xc0 = reinterpret_cast<const f32x2*>(xb + part*4)[0];   // x(0) half
        xc1 = reinterpret_cast<const f32x2*>(xb + part*4)[1];
    }
    int xoff = DIN;          // float offset of next x prefetch (t=1)
    int o2   = 0;            // running h2-store offset: (t-1)*80

    bar_lgkm();   // zero-init visible

#pragma unroll 1
    for (int t = 0; t <= TT; ++t) {
        const int p0  = t & 1;
        const int pm1 = p0 ^ 1;

        if (isL1) {
            if (t < TT) {
                const float* hin = &hb1[pm1][part << 4];
                f32x2 acc0 = {bias, 0.f}, acc1 = {0.f, 0.f};
#pragma unroll
                for (int qq = 0; qq < 4; ++qq) {
                    float4 v = reinterpret_cast<const float4*>(hin)[qq];
                    f32x2 lo = {v.x, v.y}, hi = {v.z, v.w};
                    acc0 = pkfma(wgh[2*qq],     lo, acc0);
                    acc1 = pkfma(wgh[2*qq + 1], hi, acc1);
                }
                acc0 = pkfma(wgx[0], xc0, acc0);
                acc1 = pkfma(wgx[1], xc1, acc1);
                // prefetch next x half (stays in flight across the barrier)
                xc0 = reinterpret_cast<const f32x2*>(xb + xoff + part*4)[0];
                xc1 = reinterpret_cast<const f32x2*>(xb + xoff + part*4)[1];
                xoff = (xoff + DIN > (TT-1)*DIN) ? (TT-1)*DIN : (xoff + DIN);

                float sum  = (acc0.x + acc0.y) + (acc1.x + acc1.y);
                float full = sum + dppf<0xB1>(sum);      // combine part-halves
                float u  = isg ? (full + full) : full;
                float S  = fsig(u);
                float av = isg ? (S + S - 1.0f) : S;     // tanh(g) | sigmoid
                float itg = dppf<0x114>(av) * av;        // sig(i)*tanh(g)
                float fv  = dppf<0x112>(av);             // sig(f)
                c = fv * c + itg;
                float so  = dppf<0x102>(av);             // sig(o)
                float hv  = so * ftanh_(c);
                if ((l & 7) == 4) hb1[p0][unit] = hv;    // publish h1(t)
            }
        } else {
            if (t >= 1) {
                // quad-split read: 16 floats of (input=part, half=g&1)
                const int hs = g & 1;
                const float* hin = part ? &hb1[pm1][hs << 4] : &hb2[p0][hs << 4];
                f32x2 aE0 = {0.f,0.f}, aE1 = {0.f,0.f};
                f32x2 aO0 = {0.f,0.f}, aO1 = {0.f,0.f};
#pragma unroll
                for (int qq = 0; qq < 4; ++qq) {
                    float4 v = reinterpret_cast<const float4*>(hin)[qq];
                    f32x2 lo = {v.x, v.y}, hi = {v.z, v.w};
                    aE0 = pkfma(wa2[2*qq],     lo, aE0);
                    aE1 = pkfma(wa2[2*qq + 1], hi, aE1);
                    aO0 = pkfma(wb2[2*qq],     lo, aO0);
                    aO1 = pkfma(wb2[2*qq + 1], hi, aO1);
                }
                float accE = (aE0.x + aE0.y) + (aE1.x + aE1.y);
                float accO = (aO0.x + aO0.y) + (aO1.x + aO1.y);
                // step 1 (XOR-1, other input, same hs): combine h1+h2 partials
                accE += dppf<0xB1>(accE);
                accO += dppf<0xB1>(accO);
                // step 2 (XOR-2, other hs & other row-owner): swap complements
                float stage = hs ? accE : accO;   // what partner needs
                float recv  = dppf<0x4E>(stage);  // partner's complement of MY row
                float own   = hs ? accO : accE;
                float full  = own + recv + bias;  // my row's complete 64-dot

                float u  = isg ? (full + full) : full;
                float S  = fsig(u);
                float av = isg ? (S + S - 1.0f) : S;
                float itg = dppf<0x114>(av) * av;
                float fv  = dppf<0x112>(av);
                c = fv * c + itg;
                float so  = dppf<0x102>(av);
                float hv  = so * ftanh_(c);
                if ((l & 7) == 4) {
                    hb2[pm1][unit] = hv;          // publish h2(t-1) for L2
                    outb[o2 + unit] = hv;         // scratch h2 for kernel 2
                }
                o2 += 80;
            }
        }

        bar_lgkm();
    }
}

// ============================ kernel 2: out linear ============================
// out[row][0:80] = h2[row] @ Wlin^T + blin, h2 scratch = out[row][0:32].
// Unchanged from round 11 (verified; not in top-5 dispatch cost).
__global__ void __launch_bounds__(256, 4)
out_lin(const float* __restrict__ Wlin, const float* __restrict__ blin,
        float* __restrict__ out, int ntiles)
{
    __shared__ float wl[80][36];
    __shared__ float bl[80];
    __shared__ float ht[16][36];
    const int tid = threadIdx.x;

#pragma unroll 1
    for (int i = tid; i < 640; i += 256) {          // 80 rows x 8 float4
        const int cc = i >> 3, qq = i & 7;
        float4 v = reinterpret_cast<const float4*>(Wlin)[i];
        *reinterpret_cast<float4*>(&wl[cc][qq*4]) = v;
    }
    if (tid < 80) bl[tid] = blin[tid];
    __syncthreads();

    const int row = tid >> 4;   // 0..15
    const int cl  = tid & 15;   // 0..15

#pragma unroll 1
    for (int tile = blockIdx.x; tile < ntiles; tile += gridDim.x) {
        const size_t base = (size_t)tile * 16;
        if (tid < 128) {                            // stage 16 rows of h2
            const int r = tid >> 3, qq = tid & 7;
            float4 v = *reinterpret_cast<const float4*>(out + (base + r)*80 + qq*4);
            *reinterpret_cast<float4*>(&ht[r][qq*4]) = v;
        }
        __syncthreads();

        float hr[32];
#pragma unroll
        for (int j = 0; j < 8; ++j) {
            float4 v = *reinterpret_cast<const float4*>(&ht[row][j*4]);
            hr[4*j]=v.x; hr[4*j+1]=v.y; hr[4*j+2]=v.z; hr[4*j+3]=v.w;
        }
        float res[5];
#pragma unroll
        for (int cj = 0; cj < 5; ++cj) {
            const int cc = cl + 16*cj;
            float a0 = bl[cc], a1 = 0.f, a2 = 0.f, a3 = 0.f;
#pragma unroll
            for (int k = 0; k < 32; k += 4) {
                a0 += wl[cc][k]  *hr[k];   a1 += wl[cc][k+1]*hr[k+1];
                a2 += wl[cc][k+2]*hr[k+2]; a3 += wl[cc][k+3]*hr[k+3];
            }
            res[cj] = (a0 + a1) + (a2 + a3);
        }
        __syncthreads();   // ht reads complete before next tile's staging
#pragma unroll
        for (int cj = 0; cj < 5; ++cj)
            out[(base + row)*80 + cl + 16*cj] = res[cj];
    }
}

extern "C" void kernel_launch(void* const* d_in, const int* in_sizes, int n_in,
                              void* d_out, int out_size, void* d_ws, size_t ws_size,
                              hipStream_t stream) {
    const float* x    = (const float*)d_in[0];
    const float* Wih1 = (const float*)d_in[1];
    const float* Whh1 = (const float*)d_in[2];
    const float* bih1 = (const float*)d_in[3];
    const float* bhh1 = (const float*)d_in[4];
    const float* Wih2 = (const float*)d_in[5];
    const float* Whh2 = (const float*)d_in[6];
    const float* bih2 = (const float*)d_in[7];
    const float* bhh2 = (const float*)d_in[8];
    const float* Wlin = (const float*)d_in[9];
    const float* blin = (const float*)d_in[10];

    const int B = in_sizes[0] / (TT * DIN);   // 256
    const int ntiles = (B * TT) / 16;         // 16384

    hipLaunchKernelGGL(lstm_rec, dim3(B), dim3(512), 0, stream,
                       x, Wih1, Whh1, bih1, bhh1,
                       Wih2, Whh2, bih2, bhh2,
                       (float*)d_out);
    hipLaunchKernelGGL(out_lin, dim3(2048), dim3(256), 0, stream,
                       Wlin, blin, (float*)d_out, ntiles);
}